// Round 7
// baseline (71.023 us; speedup 1.0000x reference)
//
#include <hip/hip_runtime.h>

typedef __bf16 bf16x8 __attribute__((ext_vector_type(8)));
typedef float f32x4 __attribute__((ext_vector_type(4)));

__device__ __forceinline__ unsigned short f2b(float f) {
  union { float f; unsigned int u; } v;
  v.f = f;
  unsigned int r = v.u + 0x7fffu + ((v.u >> 16) & 1u);
  return (unsigned short)(r >> 16);
}
__device__ __forceinline__ float b2f_lo(unsigned int u) {
  union { unsigned int u; float f; } v;
  v.u = u << 16;
  return v.f;
}
__device__ __forceinline__ float b2f_hi(unsigned int u) {
  union { unsigned int u; float f; } v;
  v.u = u & 0xffff0000u;
  return v.f;
}

// ---------------- kernel 0: weight f32 [O][C][9] -> bf16 k-major [O][k*256+c] --
__global__ __launch_bounds__(256) void cast_weight(
    const float* __restrict__ w, unsigned short* __restrict__ wb) {
  int idx = blockIdx.x * 256 + threadIdx.x;  // 589824
  int o = idx / 2304;
  int r = idx - o * 2304;
  int k = r >> 8;
  int c = r & 255;
  wb[idx] = f2b(w[(size_t)(o * 256 + c) * 9 + k]);
}

// ---------------- kernel 1: x NCHW f32 -> NHWC bf16  x_t[b][h][w][c] ----------
// grid 1024 = (b, h, cq): 4 blocks/CU for latency hiding.
__global__ __launch_bounds__(256) void transpose_x(
    const float* __restrict__ x, unsigned short* __restrict__ xt) {
  const int bid = blockIdx.x;
  const int b = bid >> 8;
  const int h = (bid >> 2) & 63;
  const int cq = bid & 3;
  const int t = threadIdx.x;
  const int wave = t >> 6, lane = t & 63;
  __shared__ float lds[64][65];
  const int wpos = t >> 2, sub = t & 3;
  const int cl0 = wave * 4 + (lane >> 4);
  const int w0 = (lane & 15) * 4;
#pragma unroll
  for (int iter = 0; iter < 4; ++iter) {
    const int cl = iter * 16 + cl0;
    const int c = cq * 64 + cl;
    float4 v = *(const float4*)(x + (((size_t)b * 256 + c) * 64 + h) * 64 + w0);
    lds[cl][w0] = v.x; lds[cl][w0 + 1] = v.y;
    lds[cl][w0 + 2] = v.z; lds[cl][w0 + 3] = v.w;
  }
  __syncthreads();
  unsigned short hb[16];
#pragma unroll
  for (int j = 0; j < 16; ++j) hb[j] = f2b(lds[sub * 16 + j][wpos]);
  uint4 p0, p1;
  p0.x = (unsigned)hb[0] | ((unsigned)hb[1] << 16);
  p0.y = (unsigned)hb[2] | ((unsigned)hb[3] << 16);
  p0.z = (unsigned)hb[4] | ((unsigned)hb[5] << 16);
  p0.w = (unsigned)hb[6] | ((unsigned)hb[7] << 16);
  p1.x = (unsigned)hb[8] | ((unsigned)hb[9] << 16);
  p1.y = (unsigned)hb[10] | ((unsigned)hb[11] << 16);
  p1.z = (unsigned)hb[12] | ((unsigned)hb[13] << 16);
  p1.w = (unsigned)hb[14] | ((unsigned)hb[15] << 16);
  unsigned short* dst = xt + (((size_t)b * 64 + h) * 64 + wpos) * 256 + cq * 64 + sub * 16;
  *(uint4*)dst = p0;
  *(uint4*)(dst + 8) = p1;
}

// ---------------- fused: sample + GEMM, BK=64 phases, 2 blocks x 8 waves /CU --
// block = (b, nt=h, nh=half-row). Out tile [256 o][32 hw]. 36 phases of K=64.
// 512 threads = 8 waves, 8-way m-split (32 rows each), fm=2 x fn=2.
#define G2L(gsrc, ldst)                                                            \
  __builtin_amdgcn_global_load_lds(                                                \
      (const __attribute__((address_space(1))) void*)(gsrc),                       \
      (__attribute__((address_space(3))) void*)(ldst), 16, 0, 0)

__device__ __forceinline__ void combine4(uint2 q0, uint2 q1, uint2 q2, uint2 q3,
                                         float4 wt, __bf16* dst) {
  float v0 = wt.x * b2f_lo(q0.x) + wt.y * b2f_lo(q1.x) +
             wt.z * b2f_lo(q2.x) + wt.w * b2f_lo(q3.x);
  float v1 = wt.x * b2f_hi(q0.x) + wt.y * b2f_hi(q1.x) +
             wt.z * b2f_hi(q2.x) + wt.w * b2f_hi(q3.x);
  float v2 = wt.x * b2f_lo(q0.y) + wt.y * b2f_lo(q1.y) +
             wt.z * b2f_lo(q2.y) + wt.w * b2f_lo(q3.y);
  float v3 = wt.x * b2f_hi(q0.y) + wt.y * b2f_hi(q1.y) +
             wt.z * b2f_hi(q2.y) + wt.w * b2f_hi(q3.y);
  uint2 r;
  r.x = (unsigned)f2b(v0) | ((unsigned)f2b(v1) << 16);
  r.y = (unsigned)f2b(v2) | ((unsigned)f2b(v3) << 16);
  *(uint2*)dst = r;
}

__global__ __launch_bounds__(512) void dcn_fused(
    const unsigned short* __restrict__ xt, const float* __restrict__ off,
    const float* __restrict__ mask, const __bf16* __restrict__ wbf,
    const float* __restrict__ bias, float* __restrict__ out) {
  extern __shared__ char smem_raw[];
  __bf16* As = (__bf16*)smem_raw;                        // 2 x 16384 el = 65536 B
  __bf16* Bs = As + 32768;                               // 2 x 2048 el  =  8192 B
  float* swt = (float*)(Bs + 4096);                      // [9][32][4] f32 = 4608 B
  unsigned short* sidx = (unsigned short*)(swt + 1152);  // [9][32][4] u16 = 2304 B

  const int bid = blockIdx.x;
  const int id = ((bid & 7) << 6) | (bid >> 3);  // bijective, XCD-contiguous (512=8*64)
  const int b = id >> 7;
  const int nt = (id >> 1) & 63;  // h row
  const int nh = id & 1;          // half: w in [nh*32, nh*32+32)

  const int tid = threadIdx.x;
  const int lane = tid & 63;
  const int wave = tid >> 6;  // 8 waves, m-split: rows wave*32..wave*32+31
  const int lh = lane & 15, lg = lane >> 4;

  // ---- precompute per-(pos,k) tap weights & packed indices ----
  if (tid < 288) {
    const int e = tid;
    const int k = e >> 5;    // 0..8
    const int pl = e & 31;   // 0..31
    const int w = nh * 32 + pl;
    float oy = off[(((size_t)b * 18 + 2 * k) * 64 + nt) * 64 + w];
    float ox = off[(((size_t)b * 18 + 2 * k + 1) * 64 + nt) * 64 + w];
    float m = mask[(((size_t)b * 9 + k) * 64 + nt) * 64 + w];
    float py = oy + (float)(nt - 1 + k / 3);
    float px = ox + (float)(w - 1 + k % 3);
    float y0f = floorf(py), x0f = floorf(px);
    float ly = py - y0f, lx = px - x0f;
    float hy = 1.f - ly, hx = 1.f - lx;
    int y0 = (int)y0f, x0 = (int)x0f;
    int y1 = y0 + 1, x1 = x0 + 1;
    bool vy0 = (y0 >= 0) && (y0 < 64);
    bool vy1 = (y1 >= 0) && (y1 < 64);
    bool vx0 = (x0 >= 0) && (x0 < 64);
    bool vx1 = (x1 >= 0) && (x1 < 64);
    int yc0 = min(max(y0, 0), 63), yc1 = min(max(y1, 0), 63);
    int xc0 = min(max(x0, 0), 63), xc1 = min(max(x1, 0), 63);
    unsigned short* sp = sidx + (k * 32 + pl) * 4;
    float* wp = swt + (k * 32 + pl) * 4;
    sp[0] = (unsigned short)(yc0 * 64 + xc0);
    sp[1] = (unsigned short)(yc0 * 64 + xc1);
    sp[2] = (unsigned short)(yc1 * 64 + xc0);
    sp[3] = (unsigned short)(yc1 * 64 + xc1);
    wp[0] = (vy0 && vx0) ? hy * hx * m : 0.f;
    wp[1] = (vy0 && vx1) ? hy * lx * m : 0.f;
    wp[2] = (vy1 && vx0) ? ly * hx * m : 0.f;
    wp[3] = (vy1 && vx1) ? ly * lx * m : 0.f;
  }

  // ---- A staging geometry: 4 G2L/phase/thread, 32-wide subtile XOR swizzle ----
  // chunk q = j*512+tid (0..2047): kh=q>>10, r=q&1023, row=r>>2, c4=r&3,
  // swz=c4^((row>>1)&3). src = wbf + row*2304 + kt*64 + kh*32 + swz*8.
  const __bf16* aSrc[4];
  int aDst[4];
#pragma unroll
  for (int j = 0; j < 4; ++j) {
    const int q = j * 512 + tid;
    const int kh = q >> 10;
    const int r = q & 1023;
    const int row = r >> 2;
    const int swz = (r & 3) ^ ((row >> 1) & 3);
    aSrc[j] = wbf + (size_t)row * 2304 + kh * 32 + swz * 8;
    aDst[j] = q * 8;
  }

  // ---- B build geometry: 16 threads per pos, 4 channels each ----
  const int pos = tid >> 4;  // 0..31
  const int ci = tid & 15;   // channel group: ch ci*4..ci*4+3 of 64
  const unsigned short* xtb = xt + (size_t)b * 1048576 + ci * 4;
  const int ci7 = ci & 7;
  const int bsw = (ci >> 3) * 1024 + pos * 32 +
                  (((ci7 >> 1) ^ ((pos >> 1) & 3)) << 3) + ((ci7 & 1) << 2);

  // ---- MFMA fragment offsets ----
  const int csw = (lg ^ ((lh >> 1) & 3)) * 8;
  int aoff[2], boff[2];
#pragma unroll
  for (int fm = 0; fm < 2; ++fm) aoff[fm] = (wave * 32 + fm * 16 + lh) * 32 + csw;
#pragma unroll
  for (int fn = 0; fn < 2; ++fn) boff[fn] = (fn * 16 + lh) * 32 + csw;

#define MFMA_PHASE(BUF)                                                            \
  do {                                                                             \
    const __bf16* Ab = As + (BUF) * 16384;                                         \
    const __bf16* Bb = Bs + (BUF) * 2048;                                          \
    bf16x8 a0[2], a1[2], b0[2], b1[2];                                             \
    _Pragma("unroll") for (int fm = 0; fm < 2; ++fm) {                             \
      a0[fm] = *(const bf16x8*)(Ab + aoff[fm]);                                    \
      a1[fm] = *(const bf16x8*)(Ab + 8192 + aoff[fm]);                             \
    }                                                                              \
    _Pragma("unroll") for (int fn = 0; fn < 2; ++fn) {                             \
      b0[fn] = *(const bf16x8*)(Bb + boff[fn]);                                    \
      b1[fn] = *(const bf16x8*)(Bb + 1024 + boff[fn]);                             \
    }                                                                              \
    _Pragma("unroll") for (int fm = 0; fm < 2; ++fm)                               \
        _Pragma("unroll") for (int fn = 0; fn < 2; ++fn) {                         \
      acc[fm][fn] = __builtin_amdgcn_mfma_f32_16x16x32_bf16(a0[fm], b0[fn],        \
                                                            acc[fm][fn], 0, 0, 0); \
      acc[fm][fn] = __builtin_amdgcn_mfma_f32_16x16x32_bf16(a1[fm], b1[fn],        \
                                                            acc[fm][fn], 0, 0, 0); \
    }                                                                              \
  } while (0)

#define WAIT_BAR(N)                                                                \
  do {                                                                             \
    asm volatile("s_waitcnt vmcnt(" #N ") lgkmcnt(0)" ::: "memory");               \
    __builtin_amdgcn_sched_barrier(0);                                             \
    __builtin_amdgcn_s_barrier();                                                  \
  } while (0)

#define STAGE_A(KT, BUF)                                                           \
  do {                                                                             \
    __bf16* AsD = As + (BUF) * 16384;                                              \
    G2L(aSrc[0] + (KT) * 64, AsD + aDst[0]);                                       \
    G2L(aSrc[1] + (KT) * 64, AsD + aDst[1]);                                       \
    G2L(aSrc[2] + (KT) * 64, AsD + aDst[2]);                                       \
    G2L(aSrc[3] + (KT) * 64, AsD + aDst[3]);                                       \
  } while (0)

#define LOADTAPS(Q0, Q1, Q2, Q3, KIDX, CO)                                         \
  do {                                                                             \
    uint2 su = *(const uint2*)(sidx + (KIDX) * 4);                                 \
    Q0 = *(const uint2*)(xtb + ((su.x & 0xFFFFu) << 8) + (CO));                    \
    Q1 = *(const uint2*)(xtb + ((su.x >> 16) << 8) + (CO));                        \
    Q2 = *(const uint2*)(xtb + ((su.y & 0xFFFFu) << 8) + (CO));                    \
    Q3 = *(const uint2*)(xtb + ((su.y >> 16) << 8) + (CO));                        \
  } while (0)

  // phase p: stage A(tile p+1); taps(tile p+2) -> QL; combine(QC = taps(p+1));
  // MFMA(tile p); counted wait retires the 4 G2L, leaves 4 taps in flight.
#define PHASE(P_, QL0, QL1, QL2, QL3, QC0, QC1, QC2, QC3)                          \
  do {                                                                             \
    const int kt1 = (P_) + 1, kt2 = (P_) + 2;                                      \
    STAGE_A(kt1, kt1 & 1);                                                         \
    __builtin_amdgcn_sched_barrier(0);                                             \
    float4 wt4 = *(const float4*)(swt + ((kt1 >> 2) * 32 + pos) * 4);              \
    LOADTAPS(QL0, QL1, QL2, QL3, (kt2 >> 2) * 32 + pos, (kt2 & 3) * 64);           \
    combine4(QC0, QC1, QC2, QC3, wt4, Bs + (kt1 & 1) * 2048 + bsw);                \
    __builtin_amdgcn_s_setprio(1);                                                 \
    MFMA_PHASE((P_) & 1);                                                          \
    __builtin_amdgcn_s_setprio(0);                                                 \
    WAIT_BAR(4);                                                                   \
  } while (0)

  f32x4 acc[2][2] = {};
  uint2 qA0, qA1, qA2, qA3, qB0, qB1, qB2, qB3;

  __syncthreads();  // swt/sidx ready

  // ---- prologue: tile0 build + tile0 A-stage + tile1 taps ----
  {
    float4 wt0 = *(const float4*)(swt + pos * 4);
    LOADTAPS(qA0, qA1, qA2, qA3, pos, 0);
    combine4(qA0, qA1, qA2, qA3, wt0, Bs + bsw);
    STAGE_A(0, 0);
    __builtin_amdgcn_sched_barrier(0);
    LOADTAPS(qB0, qB1, qB2, qB3, pos, 64);
    WAIT_BAR(4);
  }

  for (int p = 0; p < 34; p += 2) {
    PHASE(p, qA0, qA1, qA2, qA3, qB0, qB1, qB2, qB3);
    PHASE(p + 1, qB0, qB1, qB2, qB3, qA0, qA1, qA2, qA3);
  }
  // ---- tail: finish tiles 34, 35 ----
  {
    STAGE_A(35, 1);
    float4 wt4 = *(const float4*)(swt + (8 * 32 + pos) * 4);
    combine4(qB0, qB1, qB2, qB3, wt4, Bs + 2048 + bsw);
    __builtin_amdgcn_s_setprio(1);
    MFMA_PHASE(0);
    __builtin_amdgcn_s_setprio(0);
    WAIT_BAR(0);
    MFMA_PHASE(1);
  }

  // ---- epilogue ----
  float* outb = out + (size_t)b * 1048576 + (size_t)(nt * 64 + nh * 32);
#pragma unroll
  for (int fm = 0; fm < 2; ++fm) {
#pragma unroll
    for (int i = 0; i < 4; ++i) {
      const int o = wave * 32 + fm * 16 + lg * 4 + i;
      const float bs = bias[o];
      float* orow = outb + (size_t)o * 4096 + lh;
#pragma unroll
      for (int fn = 0; fn < 2; ++fn) orow[fn * 16] = acc[fm][fn][i] + bs;
    }
  }
#undef MFMA_PHASE
#undef WAIT_BAR
#undef STAGE_A
#undef LOADTAPS
#undef PHASE
}

extern "C" void kernel_launch(void* const* d_in, const int* in_sizes, int n_in,
                              void* d_out, int out_size, void* d_ws, size_t ws_size,
                              hipStream_t stream) {
  const float* x = (const float*)d_in[0];
  const float* off = (const float*)d_in[1];
  const float* mask = (const float*)d_in[2];
  const float* wgt = (const float*)d_in[3];
  const float* bias = (const float*)d_in[4];
  float* out = (float*)d_out;

  unsigned short* wbf = (unsigned short*)d_ws;   // 256*2304 bf16 = 1.2 MB
  unsigned short* xtp = wbf + 589824ull;         // 4*64*64*256 bf16 = 8.4 MB

  const int smem_bytes = 65536 + 8192 + 4608 + 2304;  // 80640 -> 2 blocks/CU
  (void)hipFuncSetAttribute(reinterpret_cast<const void*>(&dcn_fused),
                            hipFuncAttributeMaxDynamicSharedMemorySize, smem_bytes);

  cast_weight<<<2304, 256, 0, stream>>>(wgt, wbf);
  transpose_x<<<1024, 256, 0, stream>>>(x, xtp);
  dcn_fused<<<512, 512, smem_bytes, stream>>>(xtp, off, mask, (const __bf16*)wbf,
                                              bias, out);
}